// Round 12
// baseline (218.323 us; speedup 1.0000x reference)
//
#include <hip/hip_runtime.h>

#define S_LEN 2048
#define BATCH 8
#define DIM   64
#define QT    32          // queries per block (fast path)
#define NTK   16          // k-tiles of 128 (S/128)
#define NQT   128         // 16-row chunks per batch (S/16) in prep layout
#define PBP2  2056        // Pbuf pitch in shorts (2048 + 8)
#define CTXP  68          // ctx exchange pitch (floats)
#define EPSV  1e-8f

// ws layout (shorts): Q_pre [0, 1M), K_pre [1M, 2M), V_pre [2M, 3M)  => 6 MB
#define WS_K_OFF (1u << 20)
#define WS_V_OFF (1u << 21)
#define WS_NEED_BYTES (6u * 1024u * 1024u)

typedef __attribute__((ext_vector_type(8))) short short8;
typedef __attribute__((ext_vector_type(4))) short short4v;
typedef __attribute__((ext_vector_type(4))) float f32x4;

// round-to-nearest-even fp32 -> bf16 bits
__device__ __forceinline__ short bf16b(float x) {
    unsigned int u = __builtin_bit_cast(unsigned int, x);
    u = (u + 0x7fffu + ((u >> 16) & 1u)) >> 16;
    return (short)u;
}
__device__ __forceinline__ float bf2f(short s) {
    unsigned int u = ((unsigned int)(unsigned short)s) << 16;
    return __builtin_bit_cast(float, u);
}

#define LDS_BARRIER() do { \
    asm volatile("s_waitcnt lgkmcnt(0)" ::: "memory"); \
    __builtin_amdgcn_sched_barrier(0); \
    __builtin_amdgcn_s_barrier(); \
    __builtin_amdgcn_sched_barrier(0); \
} while (0)

// ---------------------------------------------------------------------------
// prep: normalize Q,K rows -> bf16 fragment-order; V -> bf16 transposed
// fragment-order. (unchanged from round 8/11 — measured-good)
// ---------------------------------------------------------------------------
__global__ __launch_bounds__(256)
void prep(const float* __restrict__ Qg, const float* __restrict__ Kg,
          const float* __restrict__ Vg, short* __restrict__ ws)
{
    const int blk = blockIdx.x;
    const int tid = threadIdx.x;
    if (blk < 512) {
        const bool isK = blk >= 256;
        const float* src = isK ? Kg : Qg;
        short* dst = ws + (isK ? WS_K_OFF : 0u);
        const int rg = (blk & 255) * 64 + (tid >> 2);   // global row (s*8+b)
        const int rq = tid & 3;
        const int s = rg >> 3, b = rg & 7;
        const float4* rp = reinterpret_cast<const float4*>(src) + (size_t)rg * 16;
        float4 v[4];
        float ss = 0.f;
        #pragma unroll
        for (int c = 0; c < 4; ++c) {
            v[c] = rp[rq * 4 + c];
            ss += v[c].x*v[c].x + v[c].y*v[c].y + v[c].z*v[c].z + v[c].w*v[c].w;
        }
        ss += __shfl_xor(ss, 1);
        ss += __shfl_xor(ss, 2);
        const float sc = 1.f / (sqrtf(ss) + EPSV);
        const float* pf = reinterpret_cast<const float*>(v);
        #pragma unroll
        for (int h = 0; h < 2; ++h) {
            const int c8 = rq * 2 + h;
            const int kk = c8 >> 2, lg = c8 & 3;
            const int chunk = (b * NQT + (s >> 4)) * 128 + kk * 64 + lg * 16 + (s & 15);
            short8 o;
            #pragma unroll
            for (int j = 0; j < 8; ++j) o[j] = bf16b(pf[h * 8 + j] * sc);
            *reinterpret_cast<short8*>(dst + (size_t)chunk * 8) = o;
        }
    } else {
        const int cid = (blk - 512) * 256 + tid;
        const int l  = cid & 63;
        const int kk = (cid >> 6) & 1;
        const int gd = (cid >> 7) & 3;
        const int t  = (cid >> 9) & 31;
        const int b  = cid >> 14;
        const int d  = gd * 16 + (l & 15);
        const int k0 = t * 64 + kk * 32 + (l >> 4) * 8;
        short8 o;
        #pragma unroll
        for (int j = 0; j < 8; ++j)
            o[j] = bf16b(Vg[((size_t)(k0 + j) * BATCH + b) * DIM + d]);
        *reinterpret_cast<short8*>(ws + WS_V_OFF + (size_t)cid * 8) = o;
    }
}

// ---------------------------------------------------------------------------
// Fast path v4 — SINGLE PASS. 512 blocks (1/CU, LDS-bound), 8 waves.
// k-loop (barrier-free): wave w owns k-granule w; QK^T -> exp -> bf16 into
// LDS Pbuf[32][2056] (131.6 KB) + row-sum accumulation. One barrier.
// Finale: (a) normalized attn stream from Pbuf (nontemporal, coalesced),
// (b) PV from Pbuf (wave = d-granule x k-half), ctx halves combined via an
// LDS overlay on the dead Pbuf. All barriers LDS-only (no store drain).
// ---------------------------------------------------------------------------
__global__ __launch_bounds__(512, 2)
void qattn4(const short* __restrict__ Qp, const short* __restrict__ Kp,
            const short* __restrict__ Vp, float* __restrict__ out)
{
    __shared__ short Pbuf[QT * PBP2];   // 131584 B: unnormalized exp, bf16
    __shared__ float rsum[QT];

    const int tid = threadIdx.x;
    const int l   = tid & 63;
    const int w   = tid >> 6;        // 0..7
    const int lg  = l >> 4;
    const int lr  = l & 15;

    const int b     = blockIdx.x & 7;     // batch == XCD slot
    const int qt    = blockIdx.x >> 3;    // 0..63
    const int qbase = qt * QT;

    // Q A-fragments for both 16-row strips
    const short8* Qp8 = reinterpret_cast<const short8*>(Qp);
    short8 aq[2][2];
    #pragma unroll
    for (int m = 0; m < 2; ++m) {
        const size_t base = (size_t)(b * NQT + qt * 2 + m) * 128;
        aq[m][0] = Qp8[base + l];
        aq[m][1] = Qp8[base + 64 + l];
    }

    if (tid < QT) rsum[tid] = 0.f;
    __syncthreads();

    const short8* Kb8 = reinterpret_cast<const short8*>(Kp) + (size_t)b * NQT * 128;
    const short8* Vb8 = reinterpret_cast<const short8*>(Vp) + (size_t)b * 32 * 4 * 128;

    // ================= single k-sweep: exp -> LDS, sums (no barriers) =========
    float sums[2][4] = {{0.f,0.f,0.f,0.f},{0.f,0.f,0.f,0.f}};
    short8 k0 = Kb8[(size_t)w * 128 + l];
    short8 k1 = Kb8[(size_t)w * 128 + 64 + l];
    for (int t = 0; t < NTK; ++t) {
        const int tn = (t + 1 < NTK) ? t + 1 : t;
        const short8* kc = &Kb8[(size_t)(8 * tn + w) * 128 + l];
        const short8 kn0 = kc[0];
        const short8 kn1 = kc[64];
        #pragma unroll
        for (int m = 0; m < 2; ++m) {
            f32x4 acc = {0.f, 0.f, 0.f, 0.f};
            acc = __builtin_amdgcn_mfma_f32_16x16x32_bf16(aq[m][0], k0, acc, 0, 0, 0);
            acc = __builtin_amdgcn_mfma_f32_16x16x32_bf16(aq[m][1], k1, acc, 0, 0, 0);
            #pragma unroll
            for (int r = 0; r < 4; ++r) {
                const float c = acc[r];
                const float e = __expf(0.5f + 0.5f * c * c);
                sums[m][r] += e;
                Pbuf[(m * 16 + lg * 4 + r) * PBP2 + t * 128 + w * 16 + lr] = bf16b(e);
            }
        }
        k0 = kn0; k1 = kn1;
    }
    // row sums: reduce over 16 lr lanes, then across 8 waves via LDS atomics
    #pragma unroll
    for (int m = 0; m < 2; ++m)
    #pragma unroll
    for (int r = 0; r < 4; ++r) {
        float v = sums[m][r];
        v += __shfl_xor(v, 1);
        v += __shfl_xor(v, 2);
        v += __shfl_xor(v, 4);
        v += __shfl_xor(v, 8);
        sums[m][r] = v;
    }
    if (lr == 0) {
        #pragma unroll
        for (int m = 0; m < 2; ++m)
        #pragma unroll
        for (int r = 0; r < 4; ++r)
            atomicAdd(&rsum[m * 16 + lg * 4 + r], sums[m][r]);
    }
    LDS_BARRIER();   // Pbuf + rsum complete, visible to all waves

    // ================= finale (a): normalized attn stream =====================
    float* attn = out + (size_t)S_LEN * BATCH * DIM;
    {
        const int q   = tid >> 4;
        const int l16 = tid & 15;
        const float invq = 1.f / rsum[q];
        float* dstrow = attn + (size_t)(qbase + q) * (BATCH * S_LEN) + b * S_LEN;
        #pragma unroll 4
        for (int it = 0; it < 16; ++it) {
            const int cb = it * 128 + l16 * 8;
            const short8 pv = *reinterpret_cast<const short8*>(&Pbuf[q * PBP2 + cb]);
            f32x4 o0, o1;
            #pragma unroll
            for (int j = 0; j < 4; ++j) {
                o0[j] = bf2f(pv[j])     * invq;
                o1[j] = bf2f(pv[4 + j]) * invq;
            }
            __builtin_nontemporal_store(o0, reinterpret_cast<f32x4*>(dstrow + cb));
            __builtin_nontemporal_store(o1, reinterpret_cast<f32x4*>(dstrow + cb + 4));
        }
    }

    // ================= finale (b): PV from Pbuf ===============================
    const int dg = w & 3;    // d-granule
    const int kh = w >> 2;   // k-half (0: keys 0..1023, 1: 1024..2047)
    f32x4 cacc[2];
    cacc[0] = (f32x4){0.f, 0.f, 0.f, 0.f};
    cacc[1] = (f32x4){0.f, 0.f, 0.f, 0.f};
    for (int ks = 0; ks < 32; ++ks) {
        const int t64 = kh * 16 + (ks >> 1);
        const int kk  = ks & 1;
        const short8 bv = Vb8[(size_t)(t64 * 4 + dg) * 128 + kk * 64 + l];
        const int kb = kh * 1024 + ks * 32;
        #pragma unroll
        for (int m = 0; m < 2; ++m) {
            const short8 ap = *reinterpret_cast<const short8*>(
                &Pbuf[(m * 16 + lr) * PBP2 + kb + lg * 8]);
            cacc[m] = __builtin_amdgcn_mfma_f32_16x16x32_bf16(ap, bv, cacc[m], 0, 0, 0);
        }
    }
    float invr[2][4];
    #pragma unroll
    for (int m = 0; m < 2; ++m)
    #pragma unroll
    for (int r = 0; r < 4; ++r)
        invr[m][r] = 1.f / rsum[m * 16 + lg * 4 + r];

    // combine k-halves through an overlay on the (now dead) Pbuf
    LDS_BARRIER();   // all Pbuf reads (attn + PV) complete
    float* ctxb = reinterpret_cast<float*>(Pbuf);   // [32][CTXP]
    if (kh == 1) {
        #pragma unroll
        for (int m = 0; m < 2; ++m)
        #pragma unroll
        for (int r = 0; r < 4; ++r)
            ctxb[(m * 16 + lg * 4 + r) * CTXP + dg * 16 + lr] = cacc[m][r];
    }
    LDS_BARRIER();
    if (kh == 0) {
        #pragma unroll
        for (int m = 0; m < 2; ++m)
        #pragma unroll
        for (int r = 0; r < 4; ++r) {
            const int row = m * 16 + lg * 4 + r;
            const float v = (cacc[m][r] + ctxb[row * CTXP + dg * 16 + lr]) * invr[m][r];
            out[(size_t)(qbase + row) * (BATCH * DIM) + b * DIM + dg * 16 + lr] = v;
        }
    }
}

// ---------------------------------------------------------------------------
// Fallback (round-4 kernel, measured passing at 131 us kernel time): used
// when ws_size is too small for the prep buffers. Monolithic, no workspace.
// ---------------------------------------------------------------------------
#define FQT 32
#define FQP 72
#define FPP 68
#define FKT 64
#define FNT 32

__global__ __launch_bounds__(256, 4)
void qattn_fb(const float* __restrict__ Qg, const float* __restrict__ Kg,
              const float* __restrict__ Vg, float* __restrict__ out)
{
    __shared__ short Qsh[FQT * FQP];
    __shared__ short Ksh[FKT * FQP];
    __shared__ short VTs[DIM * FQP];
    __shared__ short Pb [FQT * FQP];
    __shared__ float Pf [FQT * FPP];
    __shared__ float rsum[FQT];

    const int tid = threadIdx.x;
    const int l   = tid & 63;
    const int w   = tid >> 6;
    const int lg  = l >> 4;
    const int lr  = l & 15;
    const int ms  = (w & 1) * 16;
    const int np  = (w >> 1) * 2;

    const int b     = blockIdx.x & 7;
    const int qtile = blockIdx.x >> 3;
    const int qbase = qtile * FQT;

    const int rr = tid >> 2;
    const int rq = tid & 3;

    if (tid < FQT * 4) {
        const float4* qp = reinterpret_cast<const float4*>(
            Qg + (size_t)(qbase + rr) * (BATCH * DIM) + b * DIM);
        float4 v[4];
        float ss = 0.f;
        #pragma unroll
        for (int c = 0; c < 4; ++c) {
            v[c] = qp[rq + 4 * c];
            ss += v[c].x*v[c].x + v[c].y*v[c].y + v[c].z*v[c].z + v[c].w*v[c].w;
        }
        ss += __shfl_xor(ss, 1);
        ss += __shfl_xor(ss, 2);
        const float sc = 1.f / (sqrtf(ss) + EPSV);
        #pragma unroll
        for (int c = 0; c < 4; ++c) {
            short4v s4 = { bf16b(v[c].x * sc), bf16b(v[c].y * sc),
                           bf16b(v[c].z * sc), bf16b(v[c].w * sc) };
            *reinterpret_cast<short4v*>(&Qsh[rr * FQP + rq * 4 + 16 * c]) = s4;
        }
    }
    if (tid < FQT) rsum[tid] = 0.f;
    __syncthreads();

    short8 aq[2];
    #pragma unroll
    for (int kk = 0; kk < 2; ++kk)
        aq[kk] = *reinterpret_cast<const short8*>(&Qsh[(ms + lr) * FQP + kk * 32 + lg * 8]);

    float sums[4] = {0.f, 0.f, 0.f, 0.f};
    for (int t = 0; t < FNT; ++t) {
        __syncthreads();
        {
            const float4* kp = reinterpret_cast<const float4*>(
                Kg + (size_t)(t * FKT + rr) * (BATCH * DIM) + b * DIM);
            float4 v[4];
            float ss = 0.f;
            #pragma unroll
            for (int c = 0; c < 4; ++c) {
                v[c] = kp[rq + 4 * c];
                ss += v[c].x*v[c].x + v[c].y*v[c].y + v[c].z*v[c].z + v[c].w*v[c].w;
            }
            ss += __shfl_xor(ss, 1);
            ss += __shfl_xor(ss, 2);
            const float sc = 1.f / (sqrtf(ss) + EPSV);
            #pragma unroll
            for (int c = 0; c < 4; ++c) {
                short4v s4 = { bf16b(v[c].x * sc), bf16b(v[c].y * sc),
                               bf16b(v[c].z * sc), bf16b(v[c].w * sc) };
                *reinterpret_cast<short4v*>(&Ksh[rr * FQP + rq * 4 + 16 * c]) = s4;
            }
        }
        __syncthreads();
        #pragma unroll
        for (int g = 0; g < 2; ++g) {
            f32x4 acc = {0.f, 0.f, 0.f, 0.f};
            #pragma unroll
            for (int kk = 0; kk < 2; ++kk) {
                short8 bk = *reinterpret_cast<const short8*>(
                    &Ksh[((np + g) * 16 + lr) * FQP + kk * 32 + lg * 8]);
                acc = __builtin_amdgcn_mfma_f32_16x16x32_bf16(aq[kk], bk, acc, 0, 0, 0);
            }
            #pragma unroll
            for (int r = 0; r < 4; ++r) {
                float c = acc[r];
                sums[r] += __expf(0.5f + 0.5f * c * c);
            }
        }
    }
    #pragma unroll
    for (int r = 0; r < 4; ++r) {
        float v = sums[r];
        v += __shfl_xor(v, 1);
        v += __shfl_xor(v, 2);
        v += __shfl_xor(v, 4);
        v += __shfl_xor(v, 8);
        sums[r] = v;
    }
    if (lr == 0) {
        #pragma unroll
        for (int r = 0; r < 4; ++r)
            atomicAdd(&rsum[ms + lg * 4 + r], sums[r]);
    }
    __syncthreads();
    float inv4[4];
    #pragma unroll
    for (int r = 0; r < 4; ++r)
        inv4[r] = 1.f / rsum[ms + lg * 4 + r];

    float* attn = out + (size_t)S_LEN * BATCH * DIM;
    f32x4 cacc[2];
    cacc[0] = (f32x4){0.f, 0.f, 0.f, 0.f};
    cacc[1] = (f32x4){0.f, 0.f, 0.f, 0.f};

    for (int t = 0; t < FNT; ++t) {
        __syncthreads();
        {
            const float4* kp = reinterpret_cast<const float4*>(
                Kg + (size_t)(t * FKT + rr) * (BATCH * DIM) + b * DIM);
            float4 v[4];
            float ss = 0.f;
            #pragma unroll
            for (int c = 0; c < 4; ++c) {
                v[c] = kp[rq + 4 * c];
                ss += v[c].x*v[c].x + v[c].y*v[c].y + v[c].z*v[c].z + v[c].w*v[c].w;
            }
            ss += __shfl_xor(ss, 1);
            ss += __shfl_xor(ss, 2);
            const float sc = 1.f / (sqrtf(ss) + EPSV);
            #pragma unroll
            for (int c = 0; c < 4; ++c) {
                short4v s4 = { bf16b(v[c].x * sc), bf16b(v[c].y * sc),
                               bf16b(v[c].z * sc), bf16b(v[c].w * sc) };
                *reinterpret_cast<short4v*>(&Ksh[rr * FQP + rq * 4 + 16 * c]) = s4;
            }
        }
        {
            const float4* vp = reinterpret_cast<const float4*>(
                Vg + (size_t)(t * FKT + rr) * (BATCH * DIM) + b * DIM);
            #pragma unroll
            for (int c = 0; c < 4; ++c) {
                float4 v = vp[rq + 4 * c];
                int d0 = rq * 4 + 16 * c;
                VTs[(d0 + 0) * FQP + rr] = bf16b(v.x);
                VTs[(d0 + 1) * FQP + rr] = bf16b(v.y);
                VTs[(d0 + 2) * FQP + rr] = bf16b(v.z);
                VTs[(d0 + 3) * FQP + rr] = bf16b(v.w);
            }
        }
        __syncthreads();
        #pragma unroll
        for (int g = 0; g < 2; ++g) {
            f32x4 acc = {0.f, 0.f, 0.f, 0.f};
            #pragma unroll
            for (int kk = 0; kk < 2; ++kk) {
                short8 bk = *reinterpret_cast<const short8*>(
                    &Ksh[((np + g) * 16 + lr) * FQP + kk * 32 + lg * 8]);
                acc = __builtin_amdgcn_mfma_f32_16x16x32_bf16(aq[kk], bk, acc, 0, 0, 0);
            }
            #pragma unroll
            for (int r = 0; r < 4; ++r) {
                float c = acc[r];
                float p = __expf(0.5f + 0.5f * c * c) * inv4[r];
                int q_r = ms + lg * 4 + r;
                int k_c = (np + g) * 16 + lr;
                Pf[q_r * FPP + k_c] = p;
                Pb[q_r * FQP + k_c] = bf16b(p);
            }
        }
        __syncthreads();
        #pragma unroll
        for (int g = 0; g < 2; ++g) {
            #pragma unroll
            for (int kk = 0; kk < 2; ++kk) {
                short8 ap = *reinterpret_cast<const short8*>(
                    &Pb[(ms + lr) * FQP + kk * 32 + lg * 8]);
                short8 bv = *reinterpret_cast<const short8*>(
                    &VTs[((np + g) * 16 + lr) * FQP + kk * 32 + lg * 8]);
                cacc[g] = __builtin_amdgcn_mfma_f32_16x16x32_bf16(ap, bv, cacc[g], 0, 0, 0);
            }
        }
        #pragma unroll
        for (int s = 0; s < 2; ++s) {
            int q  = s * 16 + (tid >> 4);
            int c4 = (tid & 15) * 4;
            f32x4 pv = *reinterpret_cast<const f32x4*>(&Pf[q * FPP + c4]);
            __builtin_nontemporal_store(pv, reinterpret_cast<f32x4*>(
                attn + (size_t)(qbase + q) * (BATCH * S_LEN) + b * S_LEN + t * FKT + c4));
        }
    }

    #pragma unroll
    for (int g = 0; g < 2; ++g) {
        #pragma unroll
        for (int r = 0; r < 4; ++r) {
            __builtin_nontemporal_store(cacc[g][r],
                out + (size_t)(qbase + ms + lg * 4 + r) * (BATCH * DIM)
                    + b * DIM + (np + g) * 16 + lr);
        }
    }
}

extern "C" void kernel_launch(void* const* d_in, const int* in_sizes, int n_in,
                              void* d_out, int out_size, void* d_ws, size_t ws_size,
                              hipStream_t stream)
{
    const float* q = (const float*)d_in[0];
    const float* k = (const float*)d_in[1];
    const float* v = (const float*)d_in[2];
    float* o  = (float*)d_out;

    if (ws_size >= WS_NEED_BYTES && d_ws != nullptr) {
        short* ws = (short*)d_ws;
        prep<<<1024, 256, 0, stream>>>(q, k, v, ws);
        qattn4<<<BATCH * (S_LEN / QT), 512, 0, stream>>>(ws, ws + WS_K_OFF, ws + WS_V_OFF, o);
    } else {
        qattn_fb<<<BATCH * (S_LEN / FQT), 256, 0, stream>>>(q, k, v, o);
    }
}

// Round 13
// 160.097 us; speedup vs baseline: 1.3637x; 1.3637x over previous
//
#include <hip/hip_runtime.h>

#define S_LEN 2048
#define BATCH 8
#define DIM   64
#define QT    32          // queries per block (fast path)
#define KTILE 128         // keys per k-tile (8 granules x 16)
#define NT2   16          // k-tiles (S/KTILE)
#define NQT   128         // 16-row chunks per batch (S/16) in prep layout
#define PP    132         // fp32 P pitch (floats)
#define PBP   136         // bf16 P pitch (shorts)
#define EPSV  1e-8f

// ws layout (shorts): Q_pre [0, 1M), K_pre [1M, 2M), V_pre [2M, 3M)  => 6 MB
#define WS_K_OFF (1u << 20)
#define WS_V_OFF (1u << 21)
#define WS_NEED_BYTES (6u * 1024u * 1024u)

typedef __attribute__((ext_vector_type(8))) short short8;
typedef __attribute__((ext_vector_type(4))) short short4v;
typedef __attribute__((ext_vector_type(4))) float f32x4;

// round-to-nearest-even fp32 -> bf16 bits
__device__ __forceinline__ short bf16b(float x) {
    unsigned int u = __builtin_bit_cast(unsigned int, x);
    u = (u + 0x7fffu + ((u >> 16) & 1u)) >> 16;
    return (short)u;
}

#define LDS_BARRIER() do { \
    asm volatile("s_waitcnt lgkmcnt(0)" ::: "memory"); \
    __builtin_amdgcn_sched_barrier(0); \
    __builtin_amdgcn_s_barrier(); \
    __builtin_amdgcn_sched_barrier(0); \
} while (0)

// ---------------------------------------------------------------------------
// prep: normalize Q,K rows -> bf16 fragment-order; V -> bf16 transposed
// fragment-order. (unchanged — measured-good)
// ---------------------------------------------------------------------------
__global__ __launch_bounds__(256)
void prep(const float* __restrict__ Qg, const float* __restrict__ Kg,
          const float* __restrict__ Vg, short* __restrict__ ws)
{
    const int blk = blockIdx.x;
    const int tid = threadIdx.x;
    if (blk < 512) {
        const bool isK = blk >= 256;
        const float* src = isK ? Kg : Qg;
        short* dst = ws + (isK ? WS_K_OFF : 0u);
        const int rg = (blk & 255) * 64 + (tid >> 2);   // global row (s*8+b)
        const int rq = tid & 3;
        const int s = rg >> 3, b = rg & 7;
        const float4* rp = reinterpret_cast<const float4*>(src) + (size_t)rg * 16;
        float4 v[4];
        float ss = 0.f;
        #pragma unroll
        for (int c = 0; c < 4; ++c) {
            v[c] = rp[rq * 4 + c];
            ss += v[c].x*v[c].x + v[c].y*v[c].y + v[c].z*v[c].z + v[c].w*v[c].w;
        }
        ss += __shfl_xor(ss, 1);
        ss += __shfl_xor(ss, 2);
        const float sc = 1.f / (sqrtf(ss) + EPSV);
        const float* pf = reinterpret_cast<const float*>(v);
        #pragma unroll
        for (int h = 0; h < 2; ++h) {
            const int c8 = rq * 2 + h;
            const int kk = c8 >> 2, lg = c8 & 3;
            const int chunk = (b * NQT + (s >> 4)) * 128 + kk * 64 + lg * 16 + (s & 15);
            short8 o;
            #pragma unroll
            for (int j = 0; j < 8; ++j) o[j] = bf16b(pf[h * 8 + j] * sc);
            *reinterpret_cast<short8*>(dst + (size_t)chunk * 8) = o;
        }
    } else {
        const int cid = (blk - 512) * 256 + tid;
        const int l  = cid & 63;
        const int kk = (cid >> 6) & 1;
        const int gd = (cid >> 7) & 3;
        const int t  = (cid >> 9) & 31;
        const int b  = cid >> 14;
        const int d  = gd * 16 + (l & 15);
        const int k0 = t * 64 + kk * 32 + (l >> 4) * 8;
        short8 o;
        #pragma unroll
        for (int j = 0; j < 8; ++j)
            o[j] = bf16b(Vg[((size_t)(k0 + j) * BATCH + b) * DIM + d]);
        *reinterpret_cast<short8*>(ws + WS_V_OFF + (size_t)cid * 8) = o;
    }
}

// ---------------------------------------------------------------------------
// Fast path v5: qattn3 structure + double-buffered P (ONE LDS barrier per
// tile) + PLAIN stores (no nontemporal; L2/L3 aggregates writeback).
// 512 blocks (2/CU), 8 waves. QK^T: wave w owns k-granule w. PV: wave w =
// (mstrip=w>>2, dgran=w&3). K prefetched one tile ahead in registers.
// Dbuf safety: a wave reaches QK(t+2)'s overwrite of buf[t&1] only after
// collective bar(t+1), which requires all waves' PV(t) reads done.
// ---------------------------------------------------------------------------
__global__ __launch_bounds__(512, 4)
void qattn5(const short* __restrict__ Qp, const short* __restrict__ Kp,
            const short* __restrict__ Vp, float* __restrict__ out)
{
    __shared__ float Pf[2][QT * PP];    // probs fp32 (coalesced attn write)
    __shared__ short Pb[2][QT * PBP];   // probs bf16 (PV A-operand)
    __shared__ float rsum[QT];

    const int tid = threadIdx.x;
    const int l   = tid & 63;
    const int w   = tid >> 6;        // 0..7
    const int lg  = l >> 4;
    const int lr  = l & 15;
    const int kg  = w;               // QK phase: k-granule
    const int ms  = (w >> 2) * 16;   // PV phase: q-strip base
    const int dg  = w & 3;           // PV phase: d-granule

    const int b     = blockIdx.x & 7;     // batch == XCD slot
    const int qt    = blockIdx.x >> 3;    // 0..63
    const int qbase = qt * QT;

    // Q A-fragments for both 16-row strips
    const short8* Qp8 = reinterpret_cast<const short8*>(Qp);
    short8 aq[2][2];
    #pragma unroll
    for (int m = 0; m < 2; ++m) {
        const size_t base = (size_t)(b * NQT + qt * 2 + m) * 128;
        aq[m][0] = Qp8[base + l];
        aq[m][1] = Qp8[base + 64 + l];
    }

    if (tid < QT) rsum[tid] = 0.f;
    __syncthreads();

    const short8* Kb8 = reinterpret_cast<const short8*>(Kp) + (size_t)b * NQT * 128;
    const short8* Vb8 = reinterpret_cast<const short8*>(Vp) + (size_t)b * 32 * 4 * 128;

    // ===================== PASS A: row sums (no barriers) =====================
    float sums[2][4] = {{0.f,0.f,0.f,0.f},{0.f,0.f,0.f,0.f}};
    short8 k0 = Kb8[(size_t)kg * 128 + l];
    short8 k1 = Kb8[(size_t)kg * 128 + 64 + l];
    for (int t = 0; t < NT2; ++t) {
        const int tn = (t + 1 < NT2) ? t + 1 : t;
        const short8* kc = &Kb8[(size_t)(8 * tn + kg) * 128 + l];
        const short8 kn0 = kc[0];
        const short8 kn1 = kc[64];
        #pragma unroll
        for (int m = 0; m < 2; ++m) {
            f32x4 acc = {0.f, 0.f, 0.f, 0.f};
            acc = __builtin_amdgcn_mfma_f32_16x16x32_bf16(aq[m][0], k0, acc, 0, 0, 0);
            acc = __builtin_amdgcn_mfma_f32_16x16x32_bf16(aq[m][1], k1, acc, 0, 0, 0);
            #pragma unroll
            for (int r = 0; r < 4; ++r) {
                float c = acc[r];
                sums[m][r] += __expf(0.5f + 0.5f * c * c);
            }
        }
        k0 = kn0; k1 = kn1;
    }
    #pragma unroll
    for (int m = 0; m < 2; ++m)
    #pragma unroll
    for (int r = 0; r < 4; ++r) {
        float v = sums[m][r];
        v += __shfl_xor(v, 1);
        v += __shfl_xor(v, 2);
        v += __shfl_xor(v, 4);
        v += __shfl_xor(v, 8);
        sums[m][r] = v;
    }
    if (lr == 0) {
        #pragma unroll
        for (int m = 0; m < 2; ++m)
        #pragma unroll
        for (int r = 0; r < 4; ++r)
            atomicAdd(&rsum[m * 16 + lg * 4 + r], sums[m][r]);
    }
    __syncthreads();
    float inv_[2][4];
    #pragma unroll
    for (int m = 0; m < 2; ++m)
    #pragma unroll
    for (int r = 0; r < 4; ++r)
        inv_[m][r] = 1.f / rsum[m * 16 + lg * 4 + r];

    // ===================== PASS B: probs + attn write + PV =====================
    float* attn = out + (size_t)S_LEN * BATCH * DIM;
    f32x4 cacc = {0.f, 0.f, 0.f, 0.f};

    k0 = Kb8[(size_t)kg * 128 + l];
    k1 = Kb8[(size_t)kg * 128 + 64 + l];

    int cur = 0;
    for (int t = 0; t < NT2; ++t) {
        // issue V frags (this tile) + next K frags early
        short8 bv[4];
        #pragma unroll
        for (int kk2 = 0; kk2 < 4; ++kk2) {
            const int tv = t * 2 + (kk2 >> 1);
            bv[kk2] = Vb8[(size_t)(tv * 4 + dg) * 128 + (kk2 & 1) * 64 + l];
        }
        const int tn = (t + 1 < NT2) ? t + 1 : t;
        const short8* kc = &Kb8[(size_t)(8 * tn + kg) * 128 + l];
        const short8 kn0 = kc[0];
        const short8 kn1 = kc[64];

        // QK^T -> probs for k-granule kg, both strips (into buffer `cur`)
        float* PfC = Pf[cur];
        short* PbC = Pb[cur];
        #pragma unroll
        for (int m = 0; m < 2; ++m) {
            f32x4 acc = {0.f, 0.f, 0.f, 0.f};
            acc = __builtin_amdgcn_mfma_f32_16x16x32_bf16(aq[m][0], k0, acc, 0, 0, 0);
            acc = __builtin_amdgcn_mfma_f32_16x16x32_bf16(aq[m][1], k1, acc, 0, 0, 0);
            #pragma unroll
            for (int r = 0; r < 4; ++r) {
                float c = acc[r];
                float p = __expf(0.5f + 0.5f * c * c) * inv_[m][r];
                const int q_r = m * 16 + lg * 4 + r;
                const int k_c = kg * 16 + lr;
                PfC[q_r * PP + k_c] = p;
                PbC[q_r * PBP + k_c] = bf16b(p);
            }
        }
        LDS_BARRIER();   // P[cur] visible; prior tile's reads proven complete

        // coalesced plain attn write (32 rows x 128 cols fp32, dense 16B/lane)
        {
            const int q = tid >> 4;
            const int c = (tid & 15) * 4;
            f32x4 pv0 = *reinterpret_cast<const f32x4*>(&PfC[q * PP + c]);
            f32x4 pv1 = *reinterpret_cast<const f32x4*>(&PfC[q * PP + 64 + c]);
            float* dst = attn + (size_t)(qbase + q) * (BATCH * S_LEN) + b * S_LEN + t * KTILE;
            *reinterpret_cast<f32x4*>(dst + c)      = pv0;
            *reinterpret_cast<f32x4*>(dst + 64 + c) = pv1;
        }

        // PV accumulate: strip ms, d-granule dg, k = 0..127
        #pragma unroll
        for (int kk2 = 0; kk2 < 4; ++kk2) {
            const short8 ap = *reinterpret_cast<const short8*>(
                &PbC[(ms + lr) * PBP + kk2 * 32 + lg * 8]);
            cacc = __builtin_amdgcn_mfma_f32_16x16x32_bf16(ap, bv[kk2], cacc, 0, 0, 0);
        }

        k0 = kn0; k1 = kn1;
        cur ^= 1;
    }

    // context write: lane holds ctx[q=ms+lg*4+r][d=dg*16+lr]
    #pragma unroll
    for (int r = 0; r < 4; ++r) {
        out[(size_t)(qbase + ms + lg * 4 + r) * (BATCH * DIM) + b * DIM + dg * 16 + lr]
            = cacc[r];
    }
}

// ---------------------------------------------------------------------------
// Fallback (round-4 kernel, measured passing at 131 us kernel time): used
// when ws_size is too small for the prep buffers. Monolithic, no workspace.
// ---------------------------------------------------------------------------
#define FQT 32
#define FQP 72
#define FPP 68
#define FKT 64
#define FNT 32

__global__ __launch_bounds__(256, 4)
void qattn_fb(const float* __restrict__ Qg, const float* __restrict__ Kg,
              const float* __restrict__ Vg, float* __restrict__ out)
{
    __shared__ short Qsh[FQT * FQP];
    __shared__ short Ksh[FKT * FQP];
    __shared__ short VTs[DIM * FQP];
    __shared__ short Pb [FQT * FQP];
    __shared__ float Pf [FQT * FPP];
    __shared__ float rsum[FQT];

    const int tid = threadIdx.x;
    const int l   = tid & 63;
    const int w   = tid >> 6;
    const int lg  = l >> 4;
    const int lr  = l & 15;
    const int ms  = (w & 1) * 16;
    const int np  = (w >> 1) * 2;

    const int b     = blockIdx.x & 7;
    const int qtile = blockIdx.x >> 3;
    const int qbase = qtile * FQT;

    const int rr = tid >> 2;
    const int rq = tid & 3;

    if (tid < FQT * 4) {
        const float4* qp = reinterpret_cast<const float4*>(
            Qg + (size_t)(qbase + rr) * (BATCH * DIM) + b * DIM);
        float4 v[4];
        float ss = 0.f;
        #pragma unroll
        for (int c = 0; c < 4; ++c) {
            v[c] = qp[rq + 4 * c];
            ss += v[c].x*v[c].x + v[c].y*v[c].y + v[c].z*v[c].z + v[c].w*v[c].w;
        }
        ss += __shfl_xor(ss, 1);
        ss += __shfl_xor(ss, 2);
        const float sc = 1.f / (sqrtf(ss) + EPSV);
        #pragma unroll
        for (int c = 0; c < 4; ++c) {
            short4v s4 = { bf16b(v[c].x * sc), bf16b(v[c].y * sc),
                           bf16b(v[c].z * sc), bf16b(v[c].w * sc) };
            *reinterpret_cast<short4v*>(&Qsh[rr * FQP + rq * 4 + 16 * c]) = s4;
        }
    }
    if (tid < FQT) rsum[tid] = 0.f;
    __syncthreads();

    short8 aq[2];
    #pragma unroll
    for (int kk = 0; kk < 2; ++kk)
        aq[kk] = *reinterpret_cast<const short8*>(&Qsh[(ms + lr) * FQP + kk * 32 + lg * 8]);

    float sums[4] = {0.f, 0.f, 0.f, 0.f};
    for (int t = 0; t < FNT; ++t) {
        __syncthreads();
        {
            const float4* kp = reinterpret_cast<const float4*>(
                Kg + (size_t)(t * FKT + rr) * (BATCH * DIM) + b * DIM);
            float4 v[4];
            float ss = 0.f;
            #pragma unroll
            for (int c = 0; c < 4; ++c) {
                v[c] = kp[rq + 4 * c];
                ss += v[c].x*v[c].x + v[c].y*v[c].y + v[c].z*v[c].z + v[c].w*v[c].w;
            }
            ss += __shfl_xor(ss, 1);
            ss += __shfl_xor(ss, 2);
            const float sc = 1.f / (sqrtf(ss) + EPSV);
            #pragma unroll
            for (int c = 0; c < 4; ++c) {
                short4v s4 = { bf16b(v[c].x * sc), bf16b(v[c].y * sc),
                               bf16b(v[c].z * sc), bf16b(v[c].w * sc) };
                *reinterpret_cast<short4v*>(&Ksh[rr * FQP + rq * 4 + 16 * c]) = s4;
            }
        }
        __syncthreads();
        #pragma unroll
        for (int g = 0; g < 2; ++g) {
            f32x4 acc = {0.f, 0.f, 0.f, 0.f};
            #pragma unroll
            for (int kk = 0; kk < 2; ++kk) {
                short8 bk = *reinterpret_cast<const short8*>(
                    &Ksh[((np + g) * 16 + lr) * FQP + kk * 32 + lg * 8]);
                acc = __builtin_amdgcn_mfma_f32_16x16x32_bf16(aq[kk], bk, acc, 0, 0, 0);
            }
            #pragma unroll
            for (int r = 0; r < 4; ++r) {
                float c = acc[r];
                sums[r] += __expf(0.5f + 0.5f * c * c);
            }
        }
    }
    #pragma unroll
    for (int r = 0; r < 4; ++r) {
        float v = sums[r];
        v += __shfl_xor(v, 1);
        v += __shfl_xor(v, 2);
        v += __shfl_xor(v, 4);
        v += __shfl_xor(v, 8);
        sums[r] = v;
    }
    if (lr == 0) {
        #pragma unroll
        for (int r = 0; r < 4; ++r)
            atomicAdd(&rsum[ms + lg * 4 + r], sums[r]);
    }
    __syncthreads();
    float inv4[4];
    #pragma unroll
    for (int r = 0; r < 4; ++r)
        inv4[r] = 1.f / rsum[ms + lg * 4 + r];

    float* attn = out + (size_t)S_LEN * BATCH * DIM;
    f32x4 cacc[2];
    cacc[0] = (f32x4){0.f, 0.f, 0.f, 0.f};
    cacc[1] = (f32x4){0.f, 0.f, 0.f, 0.f};

    for (int t = 0; t < FNT; ++t) {
        __syncthreads();
        {
            const float4* kp = reinterpret_cast<const float4*>(
                Kg + (size_t)(t * FKT + rr) * (BATCH * DIM) + b * DIM);
            float4 v[4];
            float ss = 0.f;
            #pragma unroll
            for (int c = 0; c < 4; ++c) {
                v[c] = kp[rq + 4 * c];
                ss += v[c].x*v[c].x + v[c].y*v[c].y + v[c].z*v[c].z + v[c].w*v[c].w;
            }
            ss += __shfl_xor(ss, 1);
            ss += __shfl_xor(ss, 2);
            const float sc = 1.f / (sqrtf(ss) + EPSV);
            #pragma unroll
            for (int c = 0; c < 4; ++c) {
                short4v s4 = { bf16b(v[c].x * sc), bf16b(v[c].y * sc),
                               bf16b(v[c].z * sc), bf16b(v[c].w * sc) };
                *reinterpret_cast<short4v*>(&Ksh[rr * FQP + rq * 4 + 16 * c]) = s4;
            }
        }
        {
            const float4* vp = reinterpret_cast<const float4*>(
                Vg + (size_t)(t * FKT + rr) * (BATCH * DIM) + b * DIM);
            #pragma unroll
            for (int c = 0; c < 4; ++c) {
                float4 v = vp[rq + 4 * c];
                int d0 = rq * 4 + 16 * c;
                VTs[(d0 + 0) * FQP + rr] = bf16b(v.x);
                VTs[(d0 + 1) * FQP + rr] = bf16b(v.y);
                VTs[(d0 + 2) * FQP + rr] = bf16b(v.z);
                VTs[(d0 + 3) * FQP + rr] = bf16b(v.w);
            }
        }
        __syncthreads();
        #pragma unroll
        for (int g = 0; g < 2; ++g) {
            f32x4 acc = {0.f, 0.f, 0.f, 0.f};
            #pragma unroll
            for (int kk = 0; kk < 2; ++kk) {
                short8 bk = *reinterpret_cast<const short8*>(
                    &Ksh[((np + g) * 16 + lr) * FQP + kk * 32 + lg * 8]);
                acc = __builtin_amdgcn_mfma_f32_16x16x32_bf16(aq[kk], bk, acc, 0, 0, 0);
            }
            #pragma unroll
            for (int r = 0; r < 4; ++r) {
                float c = acc[r];
                float p = __expf(0.5f + 0.5f * c * c) * inv4[r];
                int q_r = ms + lg * 4 + r;
                int k_c = (np + g) * 16 + lr;
                Pf[q_r * FPP + k_c] = p;
                Pb[q_r * FQP + k_c] = bf16b(p);
            }
        }
        __syncthreads();
        #pragma unroll
        for (int g = 0; g < 2; ++g) {
            #pragma unroll
            for (int kk = 0; kk < 2; ++kk) {
                short8 ap = *reinterpret_cast<const short8*>(
                    &Pb[(ms + lr) * FQP + kk * 32 + lg * 8]);
                short8 bv = *reinterpret_cast<const short8*>(
                    &VTs[((np + g) * 16 + lr) * FQP + kk * 32 + lg * 8]);
                cacc[g] = __builtin_amdgcn_mfma_f32_16x16x32_bf16(ap, bv, cacc[g], 0, 0, 0);
            }
        }
        #pragma unroll
        for (int s = 0; s < 2; ++s) {
            int q  = s * 16 + (tid >> 4);
            int c4 = (tid & 15) * 4;
            f32x4 pv = *reinterpret_cast<const f32x4*>(&Pf[q * FPP + c4]);
            __builtin_nontemporal_store(pv, reinterpret_cast<f32x4*>(
                attn + (size_t)(qbase + q) * (BATCH * S_LEN) + b * S_LEN + t * FKT + c4));
        }
    }

    #pragma unroll
    for (int g = 0; g < 2; ++g) {
        #pragma unroll
        for (int r = 0; r < 4; ++r) {
            __builtin_nontemporal_store(cacc[g][r],
                out + (size_t)(qbase + ms + lg * 4 + r) * (BATCH * DIM)
                    + b * DIM + (np + g) * 16 + lr);
        }
    }
}

extern "C" void kernel_launch(void* const* d_in, const int* in_sizes, int n_in,
                              void* d_out, int out_size, void* d_ws, size_t ws_size,
                              hipStream_t stream)
{
    const float* q = (const float*)d_in[0];
    const float* k = (const float*)d_in[1];
    const float* v = (const float*)d_in[2];
    float* o  = (float*)d_out;

    if (ws_size >= WS_NEED_BYTES && d_ws != nullptr) {
        short* ws = (short*)d_ws;
        prep<<<1024, 256, 0, stream>>>(q, k, v, ws);
        qattn5<<<BATCH * (S_LEN / QT), 512, 0, stream>>>(ws, ws + WS_K_OFF, ws + WS_V_OFF, o);
    } else {
        qattn_fb<<<BATCH * (S_LEN / FQT), 256, 0, stream>>>(q, k, v, o);
    }
}